// Round 1
// 235.508 us; speedup vs baseline: 1.0411x; 1.0411x over previous
//
#include <hip/hip_runtime.h>
#include <hip/hip_bf16.h>
#include <math.h>

#define B_ 32
#define C_ 512
#define N_ 1024
#define D_ 64
#define OPAD 640   // D + C = 576 output channels, padded to 640 for 128-row tiles

typedef __attribute__((ext_vector_type(4))) float f32x4;
typedef __attribute__((ext_vector_type(4))) float float4v;
typedef __attribute__((ext_vector_type(8))) __bf16 bf16x8;

#define MFMA16(a, b, c) __builtin_amdgcn_mfma_f32_16x16x32_bf16((a), (b), (c), 0, 0, 0)

__device__ inline void load_lds16(const void* g, void* l) {
    __builtin_amdgcn_global_load_lds(
        (const __attribute__((address_space(1))) void*)g,
        (__attribute__((address_space(3))) void*)l, 16, 0, 0);
}

// ---------------------------------------------------------------------------
// K1a: cast w1 (rows 0..63) + w2 (rows 64..575) into bf16 W [640,512]
// ---------------------------------------------------------------------------
__global__ void k_cast_weights(const float* __restrict__ w1,
                               const float* __restrict__ w2,
                               __hip_bfloat16* __restrict__ Wbf) {
    int idx = blockIdx.x * 256 + threadIdx.x;
    if (idx >= OPAD * C_) return;
    int m = idx >> 9;
    int k = idx & (C_ - 1);
    float val = (m < D_) ? w1[m * C_ + k]
              : (m < D_ + C_) ? w2[(m - D_) * C_ + k] : 0.0f;
    Wbf[idx] = __float2bfloat16(val);
}

// ---------------------------------------------------------------------------
// K1b: transpose-cast x [B,C,N] fp32 -> xT [B,N,C] bf16.
// ---------------------------------------------------------------------------
__global__ __launch_bounds__(256) void k_transpose_cast(
        const float* __restrict__ x, __hip_bfloat16* __restrict__ xT) {
    __shared__ float tile[64][68];
    int b = blockIdx.z;
    int n0 = blockIdx.x * 64;
    int c0 = blockIdx.y * 64;
    int t = threadIdx.x;
    const float* xb = x + (size_t)b * (C_ * N_);
#pragma unroll
    for (int i = 0; i < 4; i++) {
        int c = i * 16 + (t >> 4);
        int nc = (t & 15) * 4;
        *(float4v*)&tile[c][nc] =
            *(const float4v*)(xb + (size_t)(c0 + c) * N_ + n0 + nc);
    }
    __syncthreads();
    __hip_bfloat16* xTb = xT + (size_t)b * (N_ * C_);
#pragma unroll
    for (int i = 0; i < 2; i++) {
        int n = i * 32 + (t >> 3);
        int cs = (t & 7) * 8;
        alignas(16) __hip_bfloat16 tmp[8];
#pragma unroll
        for (int j = 0; j < 8; j++)
            tmp[j] = __float2bfloat16(tile[cs + j][n]);
        *(bf16x8*)(xTb + (size_t)(n0 + n) * C_ + c0 + cs) = *(bf16x8*)tmp;
    }
}

// ---------------------------------------------------------------------------
// K2: LDS-staged GEMM  W[640,512] x xT -> qkT [B,N,D] + v [B,C,N].
// BK=64, XOR-swizzled LDS (chunk c of row r at c^(r&7)) -> conflict-free
// b128 frag reads, global coalescing preserved (permutation within a row).
// ---------------------------------------------------------------------------
__global__ __launch_bounds__(256) void k_gemm_qkv(
        const __hip_bfloat16* __restrict__ Wbf,
        const __hip_bfloat16* __restrict__ xT,
        const float* __restrict__ b1, const float* __restrict__ b2,
        __hip_bfloat16* __restrict__ qkT, __hip_bfloat16* __restrict__ v) {
    __shared__ __hip_bfloat16 As[128 * 64];   // 16 KB
    __shared__ __hip_bfloat16 Bs[128 * 64];   // 16 KB
    __shared__ __hip_bfloat16 epi[4][16][72];
    int b = blockIdx.z;
    int t = threadIdx.x;
    int wave = t >> 6, lane = t & 63, lr = lane & 15, quad = lane >> 4;
    int wm = wave >> 1, wn = wave & 1;
    int m_blk = blockIdx.y * 128;
    int n_blk = blockIdx.x * 128;
    const __hip_bfloat16* xTb = xT + (size_t)b * (N_ * C_);

    f32x4 acc[4][4] = {};
    for (int kk = 0; kk < C_; kk += 64) {
#pragma unroll
        for (int i = 0; i < 4; i++) {
            int id = i * 256 + t;
            int r = id >> 3, cx = id & 7;
            int gc = cx ^ (r & 7);
            load_lds16(Wbf + (size_t)(m_blk + r) * C_ + kk + gc * 8, &As[id * 8]);
            load_lds16(xTb + (size_t)(n_blk + r) * C_ + kk + gc * 8, &Bs[id * 8]);
        }
        __syncthreads();
#pragma unroll
        for (int h = 0; h < 2; h++) {
            bf16x8 af[4], bfr[4];
#pragma unroll
            for (int i = 0; i < 4; i++) {
                int ra = wm * 64 + i * 16 + lr;
                int rb = wn * 64 + i * 16 + lr;
                int q = h * 4 + quad;
                af[i]  = *(const bf16x8*)&As[ra * 64 + (q ^ (lr & 7)) * 8];
                bfr[i] = *(const bf16x8*)&Bs[rb * 64 + (q ^ (lr & 7)) * 8];
            }
#pragma unroll
            for (int mt = 0; mt < 4; mt++)
#pragma unroll
                for (int nt = 0; nt < 4; nt++)
                    acc[mt][nt] = MFMA16(af[mt], bfr[nt], acc[mt][nt]);
        }
        __syncthreads();
    }

#pragma unroll
    for (int mt = 0; mt < 4; mt++) {
        int m_frag = m_blk + wm * 64 + mt * 16;
        if (m_frag >= D_ + C_) continue;
        int m0 = m_frag + quad * 4;
        if (m_frag < D_) {
#pragma unroll
            for (int nt = 0; nt < 4; nt++) {
                int n = n_blk + wn * 64 + nt * 16 + lr;
                alignas(8) __hip_bfloat16 tmp[4];
#pragma unroll
                for (int r = 0; r < 4; r++)
                    tmp[r] = __float2bfloat16(acc[mt][nt][r] + b1[m0 + r]);
                *reinterpret_cast<short4*>(qkT + ((size_t)b * N_ + n) * D_ + m0) =
                    *reinterpret_cast<short4*>(tmp);
            }
        } else {
#pragma unroll
            for (int nt = 0; nt < 4; nt++) {
#pragma unroll
                for (int r = 0; r < 4; r++) {
                    int c = m0 - D_ + r;
                    epi[wave][quad * 4 + r][nt * 16 + lr] =
                        __float2bfloat16(acc[mt][nt][r] + b2[c]);
                }
            }
            int cbase = m_frag - D_;
            int row = lane >> 2;
#pragma unroll
            for (int it = 0; it < 2; it++) {
                int col = it * 32 + (lane & 3) * 8;
                bf16x8 frag = *(const bf16x8*)&epi[wave][row][col];
                *(bf16x8*)(v + (size_t)(b * C_ + cbase + row) * N_
                             + n_blk + wn * 64 + col) = frag;
            }
        }
    }
}

// ---------------------------------------------------------------------------
// K3: fused flash attention + PV GEMM + residual.
// Per block: 128 q-rows x 128 c-cols. No P / rowinv materialization.
// Softmax shift = diagonal s_nn = ||q_n||^2 (computed from registers at
// block start): guarantees rowsum >= 1 (diag term = e^0) and bounds
// off-diagonal exp by e^{||q_n||(||q_m||-||q_n||)} ~ e^30 — fp32/bf16 safe.
// Per K-tile (64 m): stage K[64x64] + V[128x64] via global_load_lds;
// S^T = MFMA(K-frag, Q-frag) so each lane's 4 outputs are m-contiguous
// -> single ds_write_b64 per fragment into swizzled LDS P-tile;
// then the standard PV MFMA loop consumes P as the A operand.
// ---------------------------------------------------------------------------
__global__ __launch_bounds__(256) void k_fused_attn(
        const __hip_bfloat16* __restrict__ qkT,
        const __hip_bfloat16* __restrict__ v,
        const float* __restrict__ x, float* __restrict__ out) {
    __shared__ char smem[40960];
    __hip_bfloat16* Ks = (__hip_bfloat16*)smem;            // [64][64]   8 KB
    __hip_bfloat16* Vs = (__hip_bfloat16*)(smem + 8192);   // [128][64] 16 KB
    __hip_bfloat16* Ps = (__hip_bfloat16*)(smem + 24576);  // [128][64] 16 KB
    float* Obuf = (float*)smem;                            // [64][128] fp32 (epilogue)
    __shared__ float Rs[128];                              // rowinv

    int b = blockIdx.z;
    int t = threadIdx.x;
    int wave = t >> 6, lane = t & 63, lr = lane & 15, quad = lane >> 4;
    int wm = wave >> 1, wn = wave & 1;
    int n_blk = blockIdx.y * 128;
    int c_blk = blockIdx.x * 128;
    const __hip_bfloat16* qb = qkT + (size_t)b * (N_ * D_);
    const __hip_bfloat16* vb = v + (size_t)b * (C_ * N_);

    // Q fragments (B operand of S^T): wave covers n-cols [wave*32, wave*32+32)
    union bfu { bf16x8 v; __hip_bfloat16 h[8]; };
    bf16x8 bq[2][2];
    float shift[2];
#pragma unroll
    for (int nj = 0; nj < 2; nj++) {
        int n = n_blk + wave * 32 + nj * 16 + lr;
#pragma unroll
        for (int dh = 0; dh < 2; dh++)
            bq[nj][dh] = *(const bf16x8*)(qb + (size_t)n * D_ + dh * 32 + quad * 8);
        float sq = 0.f;
#pragma unroll
        for (int dh = 0; dh < 2; dh++) {
            bfu u; u.v = bq[nj][dh];
#pragma unroll
            for (int j = 0; j < 8; j++) {
                float qv = __bfloat162float(u.h[j]);
                sq += qv * qv;
            }
        }
        sq += __shfl_xor(sq, 16);
        sq += __shfl_xor(sq, 32);   // full ||q_n||^2 (sum over all 4 quads)
        shift[nj] = sq;
    }

    f32x4 acc[4][4] = {};
    float rsum[2] = {0.f, 0.f};

    for (int kk = 0; kk < N_; kk += 64) {
        // stage K tile [64][64] and V tile [128][64], XOR-swizzled chunks
#pragma unroll
        for (int i = 0; i < 2; i++) {
            int id = i * 256 + t;
            int r = id >> 3, cx = id & 7;
            int gc = cx ^ (r & 7);
            load_lds16(qb + (size_t)(kk + r) * D_ + gc * 8, &Ks[id * 8]);
        }
#pragma unroll
        for (int i = 0; i < 4; i++) {
            int id = i * 256 + t;
            int r = id >> 3, cx = id & 7;
            int gc = cx ^ (r & 7);
            load_lds16(vb + (size_t)(c_blk + r) * N_ + kk + gc * 8, &Vs[id * 8]);
        }
        __syncthreads();

        // S^T tile [64 m][32 n] per wave; exp + rowsum + P~ write to LDS
#pragma unroll
        for (int mi = 0; mi < 4; mi++) {
            int m = mi * 16 + lr;
            bf16x8 ak0 = *(const bf16x8*)&Ks[m * 64 + ((quad) ^ (lr & 7)) * 8];
            bf16x8 ak1 = *(const bf16x8*)&Ks[m * 64 + ((4 + quad) ^ (lr & 7)) * 8];
#pragma unroll
            for (int nj = 0; nj < 2; nj++) {
                f32x4 s = {};
                s = MFMA16(ak0, bq[nj][0], s);
                s = MFMA16(ak1, bq[nj][1], s);
                alignas(8) __hip_bfloat16 tmp[4];
#pragma unroll
                for (int r = 0; r < 4; r++) {
                    float e = __expf(s[r] - shift[nj]);
                    rsum[nj] += e;
                    tmp[r] = __float2bfloat16(e);
                }
                // lane holds m = mi*16 + quad*4 + {0..3} (contiguous), col n
                int n = wave * 32 + nj * 16 + lr;
                int cx = mi * 2 + (quad >> 1);
                int slot = cx ^ (lr & 7);
                *(short4*)&Ps[n * 64 + slot * 8 + (quad & 1) * 4] =
                    *(short4*)tmp;
            }
        }
        __syncthreads();

        // PV: acc += P~ (A) x V (B)
#pragma unroll
        for (int h = 0; h < 2; h++) {
            bf16x8 af[4], bfr[4];
#pragma unroll
            for (int i = 0; i < 4; i++) {
                int ra = wm * 64 + i * 16 + lr;
                int rb = wn * 64 + i * 16 + lr;
                int q = h * 4 + quad;
                af[i]  = *(const bf16x8*)&Ps[ra * 64 + (q ^ (lr & 7)) * 8];
                bfr[i] = *(const bf16x8*)&Vs[rb * 64 + (q ^ (lr & 7)) * 8];
            }
#pragma unroll
            for (int mt = 0; mt < 4; mt++)
#pragma unroll
                for (int nt = 0; nt < 4; nt++)
                    acc[mt][nt] = MFMA16(af[mt], bfr[nt], acc[mt][nt]);
        }
        __syncthreads();
    }

    // finalize rowinv: reduce partial sums across the 4 quads
    rsum[0] += __shfl_xor(rsum[0], 16);
    rsum[0] += __shfl_xor(rsum[0], 32);
    rsum[1] += __shfl_xor(rsum[1], 16);
    rsum[1] += __shfl_xor(rsum[1], 32);
    if (quad == 0) {
        Rs[wave * 32 + lr]      = 1.0f / rsum[0];
        Rs[wave * 32 + 16 + lr] = 1.0f / rsum[1];
    }
    __syncthreads();

    // epilogue: two 64-row phases through LDS; float4 coalesced x/out
    const float* xb = x + (size_t)b * (N_ * C_);
    float* ob = out + (size_t)b * (N_ * C_);
#pragma unroll
    for (int h = 0; h < 2; h++) {
        if (wm == h) {
#pragma unroll
            for (int mt = 0; mt < 4; mt++)
#pragma unroll
                for (int nt = 0; nt < 4; nt++)
#pragma unroll
                    for (int r = 0; r < 4; r++)
                        Obuf[(mt * 16 + quad * 4 + r) * 128 + wn * 64 + nt * 16 + lr] =
                            acc[mt][nt][r];
        }
        __syncthreads();
#pragma unroll
        for (int i = 0; i < 8; i++) {
            int id = i * 256 + t;
            int rl = id >> 5;             // 0..63
            int c4 = (id & 31) * 4;       // float4 col
            int n = n_blk + h * 64 + rl;
            float ri = Rs[h * 64 + rl];
            float4v o = *(const float4v*)&Obuf[rl * 128 + c4];
            size_t gidx = (size_t)n * C_ + c_blk + c4;
            float4v xv = *(const float4v*)(xb + gidx);
            float4v res;
            res.x = xv.x + ri * o.x;
            res.y = xv.y + ri * o.y;
            res.z = xv.z + ri * o.z;
            res.w = xv.w + ri * o.w;
            *(float4v*)(ob + gidx) = res;
        }
        __syncthreads();
    }
}

// ---------------------------------------------------------------------------
extern "C" void kernel_launch(void* const* d_in, const int* in_sizes, int n_in,
                              void* d_out, int out_size, void* d_ws, size_t ws_size,
                              hipStream_t stream) {
    const float* x  = (const float*)d_in[0];
    const float* w1 = (const float*)d_in[1];
    const float* b1 = (const float*)d_in[2];
    const float* w2 = (const float*)d_in[3];
    const float* b2 = (const float*)d_in[4];
    float* out = (float*)d_out;

    char* ws = (char*)d_ws;
    size_t off = 0;
    __hip_bfloat16* Wbf = (__hip_bfloat16*)(ws + off); off += (size_t)OPAD * C_ * 2;
    __hip_bfloat16* xT  = (__hip_bfloat16*)(ws + off); off += (size_t)B_ * N_ * C_ * 2;
    __hip_bfloat16* qkT = (__hip_bfloat16*)(ws + off); off += (size_t)B_ * N_ * D_ * 2;
    __hip_bfloat16* v   = (__hip_bfloat16*)(ws + off); off += (size_t)B_ * C_ * N_ * 2;

    hipLaunchKernelGGL(k_cast_weights, dim3((OPAD * C_ + 255) / 256), dim3(256), 0, stream,
                       w1, w2, Wbf);
    hipLaunchKernelGGL(k_transpose_cast, dim3(N_ / 64, C_ / 64, B_), dim3(256), 0, stream,
                       x, xT);
    hipLaunchKernelGGL(k_gemm_qkv, dim3(N_ / 128, OPAD / 128, B_), dim3(256), 0, stream,
                       Wbf, xT, b1, b2, qkT, v);
    hipLaunchKernelGGL(k_fused_attn, dim3(C_ / 128, N_ / 128, B_), dim3(256), 0, stream,
                       qkT, v, x, out);
}

// Round 2
// 218.330 us; speedup vs baseline: 1.1230x; 1.0787x over previous
//
#include <hip/hip_runtime.h>
#include <hip/hip_bf16.h>
#include <math.h>

#define B_ 32
#define C_ 512
#define N_ 1024
#define D_ 64
#define OPAD 640   // D + C = 576 output channels, padded to 640 for 128-row tiles

typedef __attribute__((ext_vector_type(4))) float f32x4;
typedef __attribute__((ext_vector_type(4))) float float4v;
typedef __attribute__((ext_vector_type(8))) __bf16 bf16x8;

#define MFMA16(a, b, c) __builtin_amdgcn_mfma_f32_16x16x32_bf16((a), (b), (c), 0, 0, 0)

__device__ inline void load_lds16(const void* g, void* l) {
    __builtin_amdgcn_global_load_lds(
        (const __attribute__((address_space(1))) void*)g,
        (__attribute__((address_space(3))) void*)l, 16, 0, 0);
}

// ---------------------------------------------------------------------------
// K1a: cast w1 (rows 0..63) + w2 (rows 64..575) into bf16 W [640,512]
// ---------------------------------------------------------------------------
__global__ void k_cast_weights(const float* __restrict__ w1,
                               const float* __restrict__ w2,
                               __hip_bfloat16* __restrict__ Wbf) {
    int idx = blockIdx.x * 256 + threadIdx.x;
    if (idx >= OPAD * C_) return;
    int m = idx >> 9;
    int k = idx & (C_ - 1);
    float val = (m < D_) ? w1[m * C_ + k]
              : (m < D_ + C_) ? w2[(m - D_) * C_ + k] : 0.0f;
    Wbf[idx] = __float2bfloat16(val);
}

// ---------------------------------------------------------------------------
// K1b: transpose-cast x [B,C,N] fp32 -> xT [B,N,C] bf16.
// ---------------------------------------------------------------------------
__global__ __launch_bounds__(256) void k_transpose_cast(
        const float* __restrict__ x, __hip_bfloat16* __restrict__ xT) {
    __shared__ float tile[64][68];
    int b = blockIdx.z;
    int n0 = blockIdx.x * 64;
    int c0 = blockIdx.y * 64;
    int t = threadIdx.x;
    const float* xb = x + (size_t)b * (C_ * N_);
#pragma unroll
    for (int i = 0; i < 4; i++) {
        int c = i * 16 + (t >> 4);
        int nc = (t & 15) * 4;
        *(float4v*)&tile[c][nc] =
            *(const float4v*)(xb + (size_t)(c0 + c) * N_ + n0 + nc);
    }
    __syncthreads();
    __hip_bfloat16* xTb = xT + (size_t)b * (N_ * C_);
#pragma unroll
    for (int i = 0; i < 2; i++) {
        int n = i * 32 + (t >> 3);
        int cs = (t & 7) * 8;
        alignas(16) __hip_bfloat16 tmp[8];
#pragma unroll
        for (int j = 0; j < 8; j++)
            tmp[j] = __float2bfloat16(tile[cs + j][n]);
        *(bf16x8*)(xTb + (size_t)(n0 + n) * C_ + c0 + cs) = *(bf16x8*)tmp;
    }
}

// ---------------------------------------------------------------------------
// K2: LDS-staged GEMM  W[640,512] x xT -> qkT [B,N,D] + v [B,C,N].
// BK=64, XOR-swizzled LDS (chunk c of row r at c^(r&7)) -> conflict-free
// b128 frag reads, global coalescing preserved (permutation within a row).
// ---------------------------------------------------------------------------
__global__ __launch_bounds__(256) void k_gemm_qkv(
        const __hip_bfloat16* __restrict__ Wbf,
        const __hip_bfloat16* __restrict__ xT,
        const float* __restrict__ b1, const float* __restrict__ b2,
        __hip_bfloat16* __restrict__ qkT, __hip_bfloat16* __restrict__ v) {
    __shared__ __hip_bfloat16 As[128 * 64];   // 16 KB
    __shared__ __hip_bfloat16 Bs[128 * 64];   // 16 KB
    __shared__ __hip_bfloat16 epi[4][16][72];
    int b = blockIdx.z;
    int t = threadIdx.x;
    int wave = t >> 6, lane = t & 63, lr = lane & 15, quad = lane >> 4;
    int wm = wave >> 1, wn = wave & 1;
    int m_blk = blockIdx.y * 128;
    int n_blk = blockIdx.x * 128;
    const __hip_bfloat16* xTb = xT + (size_t)b * (N_ * C_);

    f32x4 acc[4][4] = {};
    for (int kk = 0; kk < C_; kk += 64) {
#pragma unroll
        for (int i = 0; i < 4; i++) {
            int id = i * 256 + t;
            int r = id >> 3, cx = id & 7;
            int gc = cx ^ (r & 7);
            load_lds16(Wbf + (size_t)(m_blk + r) * C_ + kk + gc * 8, &As[id * 8]);
            load_lds16(xTb + (size_t)(n_blk + r) * C_ + kk + gc * 8, &Bs[id * 8]);
        }
        __syncthreads();
#pragma unroll
        for (int h = 0; h < 2; h++) {
            bf16x8 af[4], bfr[4];
#pragma unroll
            for (int i = 0; i < 4; i++) {
                int ra = wm * 64 + i * 16 + lr;
                int rb = wn * 64 + i * 16 + lr;
                int q = h * 4 + quad;
                af[i]  = *(const bf16x8*)&As[ra * 64 + (q ^ (lr & 7)) * 8];
                bfr[i] = *(const bf16x8*)&Bs[rb * 64 + (q ^ (lr & 7)) * 8];
            }
#pragma unroll
            for (int mt = 0; mt < 4; mt++)
#pragma unroll
                for (int nt = 0; nt < 4; nt++)
                    acc[mt][nt] = MFMA16(af[mt], bfr[nt], acc[mt][nt]);
        }
        __syncthreads();
    }

#pragma unroll
    for (int mt = 0; mt < 4; mt++) {
        int m_frag = m_blk + wm * 64 + mt * 16;
        if (m_frag >= D_ + C_) continue;
        int m0 = m_frag + quad * 4;
        if (m_frag < D_) {
#pragma unroll
            for (int nt = 0; nt < 4; nt++) {
                int n = n_blk + wn * 64 + nt * 16 + lr;
                alignas(8) __hip_bfloat16 tmp[4];
#pragma unroll
                for (int r = 0; r < 4; r++)
                    tmp[r] = __float2bfloat16(acc[mt][nt][r] + b1[m0 + r]);
                *reinterpret_cast<short4*>(qkT + ((size_t)b * N_ + n) * D_ + m0) =
                    *reinterpret_cast<short4*>(tmp);
            }
        } else {
#pragma unroll
            for (int nt = 0; nt < 4; nt++) {
#pragma unroll
                for (int r = 0; r < 4; r++) {
                    int c = m0 - D_ + r;
                    epi[wave][quad * 4 + r][nt * 16 + lr] =
                        __float2bfloat16(acc[mt][nt][r] + b2[c]);
                }
            }
            int cbase = m_frag - D_;
            int row = lane >> 2;
#pragma unroll
            for (int it = 0; it < 2; it++) {
                int col = it * 32 + (lane & 3) * 8;
                bf16x8 frag = *(const bf16x8*)&epi[wave][row][col];
                *(bf16x8*)(v + (size_t)(b * C_ + cbase + row) * N_
                             + n_blk + wn * 64 + col) = frag;
            }
        }
    }
}

// ---------------------------------------------------------------------------
// K3: fused flash attention + PV GEMM + residual, FULL c-width per block.
// One block per (b, 128 q-rows): grid 8x32 = 256 blocks = exactly 1/CU.
// S^T + exp + Ps computed ONCE (no c-block redundancy); 8 waves (2x4):
// each wave owns a 64n x 128c output tile (acc[4][8]), and computes the
// S^T columns for its own 16 n-rows (8 MFMA + 16 exp per thread per tile).
// Softmax shift = ||q_n||^2 (diagonal), rowsum >= 1, exp <= ~e^30: fp32-safe.
// LDS: Ks[64][64] 8K + Vs[512][64] 64K + Ps[128][64] 16K = 88 KB.
// ---------------------------------------------------------------------------
__global__ __launch_bounds__(512, 2) void k_fused_attn(
        const __hip_bfloat16* __restrict__ qkT,
        const __hip_bfloat16* __restrict__ v,
        const float* __restrict__ x, float* __restrict__ out) {
    __shared__ char smem[90112];
    __hip_bfloat16* Ks = (__hip_bfloat16*)smem;            // [64][64]    8 KB
    __hip_bfloat16* Vs = (__hip_bfloat16*)(smem + 8192);   // [512][64]  64 KB
    __hip_bfloat16* Ps = (__hip_bfloat16*)(smem + 73728);  // [128][64]  16 KB
    float* Obuf = (float*)smem;                            // [64][260] fp32 epi
    __shared__ float Rs[128];

    int b = blockIdx.y;
    int t = threadIdx.x;
    int wave = t >> 6, lane = t & 63, lr = lane & 15, quad = lane >> 4;
    int wm = wave >> 2, wn = wave & 3;
    int n_blk = blockIdx.x * 128;
    const __hip_bfloat16* qb = qkT + (size_t)b * (N_ * D_);
    const __hip_bfloat16* vb = v + (size_t)b * (C_ * N_);

    // Q fragment (B operand of S^T): wave covers n-cols [wave*16, wave*16+16)
    union bfu { bf16x8 v; __hip_bfloat16 h[8]; };
    bf16x8 bq[2];
    float shift;
    {
        int nq = n_blk + wave * 16 + lr;
        bq[0] = *(const bf16x8*)(qb + (size_t)nq * D_ + quad * 8);
        bq[1] = *(const bf16x8*)(qb + (size_t)nq * D_ + 32 + quad * 8);
        float sq = 0.f;
#pragma unroll
        for (int dh = 0; dh < 2; dh++) {
            bfu u; u.v = bq[dh];
#pragma unroll
            for (int j = 0; j < 8; j++) {
                float qv = __bfloat162float(u.h[j]);
                sq += qv * qv;
            }
        }
        sq += __shfl_xor(sq, 16);
        sq += __shfl_xor(sq, 32);   // full ||q_n||^2 across the 4 quads
        shift = sq;
    }

    f32x4 acc[4][8] = {};
    float rsum = 0.f;

    for (int kk = 0; kk < N_; kk += 64) {
        // stage K tile [64][64] (1 load/thread) + V tile [512][64] (8 loads)
        {
            int r = t >> 3, cx = t & 7, gc = cx ^ (r & 7);
            load_lds16(qb + (size_t)(kk + r) * D_ + gc * 8, &Ks[t * 8]);
        }
#pragma unroll
        for (int i = 0; i < 8; i++) {
            int id = i * 512 + t;
            int r = id >> 3, cx = id & 7, gc = cx ^ (r & 7);
            load_lds16(vb + (size_t)r * N_ + kk + gc * 8, &Vs[id * 8]);
        }
        __syncthreads();

        // S^T for this wave's 16 n-cols: [64 m][16 n]; exp + rowsum + Ps
#pragma unroll
        for (int mi = 0; mi < 4; mi++) {
            int m = mi * 16 + lr;
            bf16x8 ak0 = *(const bf16x8*)&Ks[m * 64 + ((quad) ^ (lr & 7)) * 8];
            bf16x8 ak1 = *(const bf16x8*)&Ks[m * 64 + ((4 + quad) ^ (lr & 7)) * 8];
            f32x4 s = {};
            s = MFMA16(ak0, bq[0], s);
            s = MFMA16(ak1, bq[1], s);
            alignas(8) __hip_bfloat16 tmp[4];
#pragma unroll
            for (int r = 0; r < 4; r++) {
                float e = __expf(s[r] - shift);
                rsum += e;
                tmp[r] = __float2bfloat16(e);
            }
            // lane holds m = mi*16 + quad*4 + {0..3} (contiguous), col n
            int n = wave * 16 + lr;
            int cx2 = mi * 2 + (quad >> 1);
            int slot = cx2 ^ (lr & 7);
            *(short4*)&Ps[n * 64 + slot * 8 + (quad & 1) * 4] = *(short4*)tmp;
        }
        __syncthreads();

        // PV: acc[n 64][c 128] += Ps (A) x Vs (B)
#pragma unroll
        for (int h = 0; h < 2; h++) {
            bf16x8 af[4];
#pragma unroll
            for (int i = 0; i < 4; i++) {
                int ra = wm * 64 + i * 16 + lr;
                af[i] = *(const bf16x8*)&Ps[ra * 64 + ((h * 4 + quad) ^ (lr & 7)) * 8];
            }
#pragma unroll
            for (int g = 0; g < 2; g++) {
                bf16x8 bfr[4];
#pragma unroll
                for (int j = 0; j < 4; j++) {
                    int rb = wn * 128 + (g * 4 + j) * 16 + lr;
                    bfr[j] = *(const bf16x8*)&Vs[rb * 64 + ((h * 4 + quad) ^ (lr & 7)) * 8];
                }
#pragma unroll
                for (int mt = 0; mt < 4; mt++)
#pragma unroll
                    for (int j = 0; j < 4; j++)
                        acc[mt][g * 4 + j] = MFMA16(af[mt], bfr[j], acc[mt][g * 4 + j]);
            }
        }
        __syncthreads();
    }

    // rowinv: reduce partial sums across the 4 quads
    rsum += __shfl_xor(rsum, 16);
    rsum += __shfl_xor(rsum, 32);
    if (quad == 0) Rs[wave * 16 + lr] = 1.0f / rsum;

    // epilogue: 4 phases (h = n-half, g = c-half) through LDS Obuf[64][260]
    const float* xb = x + (size_t)b * (N_ * C_);
    float* ob = out + (size_t)b * (N_ * C_);
#pragma unroll
    for (int h = 0; h < 2; h++) {
#pragma unroll
        for (int g = 0; g < 2; g++) {
            __syncthreads();   // Obuf free (covers Rs on first pass)
            if (wm == h && (wn >> 1) == g) {
#pragma unroll
                for (int mt = 0; mt < 4; mt++)
#pragma unroll
                    for (int nt = 0; nt < 8; nt++)
#pragma unroll
                        for (int r = 0; r < 4; r++)
                            Obuf[(mt * 16 + quad * 4 + r) * 260
                                 + (wn & 1) * 128 + nt * 16 + lr] =
                                acc[mt][nt][r];
            }
            __syncthreads();
#pragma unroll
            for (int i = 0; i < 8; i++) {
                int id = i * 512 + t;
                int rl = id >> 6;              // 0..63 (= i*8 + wave)
                int c4 = (id & 63) * 4;        // float4 col 0..252
                int n = n_blk + h * 64 + rl;
                float ri = Rs[h * 64 + rl];
                float4v o = *(const float4v*)&Obuf[rl * 260 + c4];
                size_t gidx = (size_t)n * C_ + g * 256 + c4;
                float4v xv = *(const float4v*)(xb + gidx);
                float4v res;
                res.x = xv.x + ri * o.x;
                res.y = xv.y + ri * o.y;
                res.z = xv.z + ri * o.z;
                res.w = xv.w + ri * o.w;
                *(float4v*)(ob + gidx) = res;
            }
        }
    }
}

// ---------------------------------------------------------------------------
extern "C" void kernel_launch(void* const* d_in, const int* in_sizes, int n_in,
                              void* d_out, int out_size, void* d_ws, size_t ws_size,
                              hipStream_t stream) {
    const float* x  = (const float*)d_in[0];
    const float* w1 = (const float*)d_in[1];
    const float* b1 = (const float*)d_in[2];
    const float* w2 = (const float*)d_in[3];
    const float* b2 = (const float*)d_in[4];
    float* out = (float*)d_out;

    char* ws = (char*)d_ws;
    size_t off = 0;
    __hip_bfloat16* Wbf = (__hip_bfloat16*)(ws + off); off += (size_t)OPAD * C_ * 2;
    __hip_bfloat16* xT  = (__hip_bfloat16*)(ws + off); off += (size_t)B_ * N_ * C_ * 2;
    __hip_bfloat16* qkT = (__hip_bfloat16*)(ws + off); off += (size_t)B_ * N_ * D_ * 2;
    __hip_bfloat16* v   = (__hip_bfloat16*)(ws + off); off += (size_t)B_ * C_ * N_ * 2;

    hipLaunchKernelGGL(k_cast_weights, dim3((OPAD * C_ + 255) / 256), dim3(256), 0, stream,
                       w1, w2, Wbf);
    hipLaunchKernelGGL(k_transpose_cast, dim3(N_ / 64, C_ / 64, B_), dim3(256), 0, stream,
                       x, xT);
    hipLaunchKernelGGL(k_gemm_qkv, dim3(N_ / 128, OPAD / 128, B_), dim3(256), 0, stream,
                       Wbf, xT, b1, b2, qkT, v);
    hipLaunchKernelGGL(k_fused_attn, dim3(N_ / 128, B_), dim3(512), 0, stream,
                       qkT, v, x, out);
}

// Round 3
// 207.710 us; speedup vs baseline: 1.1804x; 1.0511x over previous
//
#include <hip/hip_runtime.h>
#include <hip/hip_bf16.h>
#include <math.h>

#define B_ 32
#define C_ 512
#define N_ 1024
#define D_ 64
#define OPAD 640   // D + C = 576 output channels, padded to 640 for 128-row tiles

typedef __attribute__((ext_vector_type(4))) float f32x4;
typedef __attribute__((ext_vector_type(4))) float float4v;
typedef __attribute__((ext_vector_type(8))) __bf16 bf16x8;

#define MFMA16(a, b, c) __builtin_amdgcn_mfma_f32_16x16x32_bf16((a), (b), (c), 0, 0, 0)

__device__ inline void load_lds16(const void* g, void* l) {
    __builtin_amdgcn_global_load_lds(
        (const __attribute__((address_space(1))) void*)g,
        (__attribute__((address_space(3))) void*)l, 16, 0, 0);
}

// ---------------------------------------------------------------------------
// K1a: cast w1 (rows 0..63) + w2 (rows 64..575) into bf16 W [640,512]
// ---------------------------------------------------------------------------
__global__ void k_cast_weights(const float* __restrict__ w1,
                               const float* __restrict__ w2,
                               __hip_bfloat16* __restrict__ Wbf) {
    int idx = blockIdx.x * 256 + threadIdx.x;
    if (idx >= OPAD * C_) return;
    int m = idx >> 9;
    int k = idx & (C_ - 1);
    float val = (m < D_) ? w1[m * C_ + k]
              : (m < D_ + C_) ? w2[(m - D_) * C_ + k] : 0.0f;
    Wbf[idx] = __float2bfloat16(val);
}

// ---------------------------------------------------------------------------
// K1b: transpose-cast x [B,C,N] fp32 -> xT [B,N,C] bf16.
// ---------------------------------------------------------------------------
__global__ __launch_bounds__(256) void k_transpose_cast(
        const float* __restrict__ x, __hip_bfloat16* __restrict__ xT) {
    __shared__ float tile[64][68];
    int b = blockIdx.z;
    int n0 = blockIdx.x * 64;
    int c0 = blockIdx.y * 64;
    int t = threadIdx.x;
    const float* xb = x + (size_t)b * (C_ * N_);
#pragma unroll
    for (int i = 0; i < 4; i++) {
        int c = i * 16 + (t >> 4);
        int nc = (t & 15) * 4;
        *(float4v*)&tile[c][nc] =
            *(const float4v*)(xb + (size_t)(c0 + c) * N_ + n0 + nc);
    }
    __syncthreads();
    __hip_bfloat16* xTb = xT + (size_t)b * (N_ * C_);
#pragma unroll
    for (int i = 0; i < 2; i++) {
        int n = i * 32 + (t >> 3);
        int cs = (t & 7) * 8;
        alignas(16) __hip_bfloat16 tmp[8];
#pragma unroll
        for (int j = 0; j < 8; j++)
            tmp[j] = __float2bfloat16(tile[cs + j][n]);
        *(bf16x8*)(xTb + (size_t)(n0 + n) * C_ + c0 + cs) = *(bf16x8*)tmp;
    }
}

// ---------------------------------------------------------------------------
// K2: LDS-staged GEMM  W[640,512] x xT -> qkT [B,N,D] + v [B,C,N].
// BK=64, XOR-swizzled LDS. Grid remapped to (b, n, m) so linear block id
// = b + 32*n + 256*m -> XCD = b%8: same-b blocks share one XCD's L2 (xT[b]).
// ---------------------------------------------------------------------------
__global__ __launch_bounds__(256) void k_gemm_qkv(
        const __hip_bfloat16* __restrict__ Wbf,
        const __hip_bfloat16* __restrict__ xT,
        const float* __restrict__ b1, const float* __restrict__ b2,
        __hip_bfloat16* __restrict__ qkT, __hip_bfloat16* __restrict__ v) {
    __shared__ __hip_bfloat16 As[128 * 64];   // 16 KB
    __shared__ __hip_bfloat16 Bs[128 * 64];   // 16 KB
    __shared__ __hip_bfloat16 epi[4][16][72];
    int b = blockIdx.x;
    int t = threadIdx.x;
    int wave = t >> 6, lane = t & 63, lr = lane & 15, quad = lane >> 4;
    int wm = wave >> 1, wn = wave & 1;
    int m_blk = blockIdx.z * 128;
    int n_blk = blockIdx.y * 128;
    const __hip_bfloat16* xTb = xT + (size_t)b * (N_ * C_);

    f32x4 acc[4][4] = {};
    for (int kk = 0; kk < C_; kk += 64) {
#pragma unroll
        for (int i = 0; i < 4; i++) {
            int id = i * 256 + t;
            int r = id >> 3, cx = id & 7;
            int gc = cx ^ (r & 7);
            load_lds16(Wbf + (size_t)(m_blk + r) * C_ + kk + gc * 8, &As[id * 8]);
            load_lds16(xTb + (size_t)(n_blk + r) * C_ + kk + gc * 8, &Bs[id * 8]);
        }
        __syncthreads();
#pragma unroll
        for (int h = 0; h < 2; h++) {
            bf16x8 af[4], bfr[4];
#pragma unroll
            for (int i = 0; i < 4; i++) {
                int ra = wm * 64 + i * 16 + lr;
                int rb = wn * 64 + i * 16 + lr;
                int q = h * 4 + quad;
                af[i]  = *(const bf16x8*)&As[ra * 64 + (q ^ (lr & 7)) * 8];
                bfr[i] = *(const bf16x8*)&Bs[rb * 64 + (q ^ (lr & 7)) * 8];
            }
#pragma unroll
            for (int mt = 0; mt < 4; mt++)
#pragma unroll
                for (int nt = 0; nt < 4; nt++)
                    acc[mt][nt] = MFMA16(af[mt], bfr[nt], acc[mt][nt]);
        }
        __syncthreads();
    }

#pragma unroll
    for (int mt = 0; mt < 4; mt++) {
        int m_frag = m_blk + wm * 64 + mt * 16;
        if (m_frag >= D_ + C_) continue;
        int m0 = m_frag + quad * 4;
        if (m_frag < D_) {
#pragma unroll
            for (int nt = 0; nt < 4; nt++) {
                int n = n_blk + wn * 64 + nt * 16 + lr;
                alignas(8) __hip_bfloat16 tmp[4];
#pragma unroll
                for (int r = 0; r < 4; r++)
                    tmp[r] = __float2bfloat16(acc[mt][nt][r] + b1[m0 + r]);
                *reinterpret_cast<short4*>(qkT + ((size_t)b * N_ + n) * D_ + m0) =
                    *reinterpret_cast<short4*>(tmp);
            }
        } else {
#pragma unroll
            for (int nt = 0; nt < 4; nt++) {
#pragma unroll
                for (int r = 0; r < 4; r++) {
                    int c = m0 - D_ + r;
                    epi[wave][quad * 4 + r][nt * 16 + lr] =
                        __float2bfloat16(acc[mt][nt][r] + b2[c]);
                }
            }
            int cbase = m_frag - D_;
            int row = lane >> 2;
#pragma unroll
            for (int it = 0; it < 2; it++) {
                int col = it * 32 + (lane & 3) * 8;
                bf16x8 frag = *(const bf16x8*)&epi[wave][row][col];
                *(bf16x8*)(v + (size_t)(b * C_ + cbase + row) * N_
                             + n_blk + wn * 64 + col) = frag;
            }
        }
    }
}

// ---------------------------------------------------------------------------
// K3: fused flash attention + PV GEMM + residual, FULL c-width per block.
// Grid (b=32, n=8): linear id = b + 32*n -> XCD = b%8, so all 8 n-blocks of
// a batch share one XCD's L2 (v[b] = 1 MB read 8x -> L2-served, not HBM).
// 1-tile software pipeline: Vs double-buffered (stage t+1 issued at tile
// start, stays in flight across the lgkm-only mid barrier, drained by the
// end-of-tile __syncthreads); Ks single-buffered, staged during PV.
// LDS: Ks 8K + Vs0 64K + Vs1 64K + Ps 16K = 152 KB (1 block/CU; grid=256).
// ---------------------------------------------------------------------------
__global__ __launch_bounds__(512, 2) void k_fused_attn(
        const __hip_bfloat16* __restrict__ qkT,
        const __hip_bfloat16* __restrict__ v,
        const float* __restrict__ x, float* __restrict__ out) {
    __shared__ char smem[155648];
    __hip_bfloat16* Ks  = (__hip_bfloat16*)smem;             // [64][64]    8 KB
    __hip_bfloat16* Vs0 = (__hip_bfloat16*)(smem + 8192);    // [512][64]  64 KB
    __hip_bfloat16* Vs1 = (__hip_bfloat16*)(smem + 73728);   // [512][64]  64 KB
    __hip_bfloat16* Ps  = (__hip_bfloat16*)(smem + 139264);  // [128][64]  16 KB
    float* Obuf = (float*)smem;                              // [64][260] fp32 epi
    float* Rs   = (float*)(smem + 66560);                    // [128] rowinv (dead Vs0)

    int b = blockIdx.x;
    int t = threadIdx.x;
    int wave = t >> 6, lane = t & 63, lr = lane & 15, quad = lane >> 4;
    int wm = wave >> 2, wn = wave & 3;
    int n_blk = blockIdx.y * 128;
    const __hip_bfloat16* qb = qkT + (size_t)b * (N_ * D_);
    const __hip_bfloat16* vb = v + (size_t)b * (C_ * N_);

    // prologue: stage tile 0 (Ks + Vs0); Q-fragment loads overlap the latency
    {
        int r = t >> 3, cxx = t & 7, gc = cxx ^ (r & 7);
        load_lds16(qb + (size_t)r * D_ + gc * 8, &Ks[t * 8]);
    }
#pragma unroll
    for (int i = 0; i < 8; i++) {
        int id = i * 512 + t;
        int r = id >> 3, cxx = id & 7, gc = cxx ^ (r & 7);
        load_lds16(vb + (size_t)r * N_ + gc * 8, &Vs0[id * 8]);
    }

    // Q fragment (B operand of S^T) + softmax shift = ||q_n||^2 (diagonal):
    // rowsum >= 1 (diag term e^0), off-diag exp <= ~e^30 -> fp32/bf16 safe.
    union bfu { bf16x8 v; __hip_bfloat16 h[8]; };
    bf16x8 bq[2];
    float shift;
    {
        int nq = n_blk + wave * 16 + lr;
        bq[0] = *(const bf16x8*)(qb + (size_t)nq * D_ + quad * 8);
        bq[1] = *(const bf16x8*)(qb + (size_t)nq * D_ + 32 + quad * 8);
        float sq = 0.f;
#pragma unroll
        for (int dh = 0; dh < 2; dh++) {
            bfu u; u.v = bq[dh];
#pragma unroll
            for (int j = 0; j < 8; j++) {
                float qv = __bfloat162float(u.h[j]);
                sq += qv * qv;
            }
        }
        sq += __shfl_xor(sq, 16);
        sq += __shfl_xor(sq, 32);   // full ||q_n||^2 across the 4 quads
        shift = sq;
    }

    f32x4 acc[4][8] = {};
    float rsum = 0.f;

    __syncthreads();   // vmcnt(0) drain: tile 0 staged

    for (int tt = 0; tt < 16; ++tt) {
        int kk = tt * 64;
        __hip_bfloat16* Vcur = (tt & 1) ? Vs1 : Vs0;
        __hip_bfloat16* Vnxt = (tt & 1) ? Vs0 : Vs1;

        // issue Vs stage for t+1 (completes under this tile's compute)
        if (tt < 15) {
#pragma unroll
            for (int i = 0; i < 8; i++) {
                int id = i * 512 + t;
                int r = id >> 3, cxx = id & 7, gc = cxx ^ (r & 7);
                load_lds16(vb + (size_t)r * N_ + kk + 64 + gc * 8, &Vnxt[id * 8]);
            }
        }

        // S-phase: this wave's 16 n-cols x 64 m; exp + rowsum + Ps write
#pragma unroll
        for (int mi = 0; mi < 4; mi++) {
            int m = mi * 16 + lr;
            bf16x8 ak0 = *(const bf16x8*)&Ks[m * 64 + ((quad) ^ (lr & 7)) * 8];
            bf16x8 ak1 = *(const bf16x8*)&Ks[m * 64 + ((4 + quad) ^ (lr & 7)) * 8];
            f32x4 s = {};
            s = MFMA16(ak0, bq[0], s);
            s = MFMA16(ak1, bq[1], s);
            alignas(8) __hip_bfloat16 tmp[4];
#pragma unroll
            for (int r = 0; r < 4; r++) {
                float e = __expf(s[r] - shift);
                rsum += e;
                tmp[r] = __float2bfloat16(e);
            }
            // lane holds m = mi*16 + quad*4 + {0..3} (contiguous), col n
            int n = wave * 16 + lr;
            int cx2 = mi * 2 + (quad >> 1);
            int slot = cx2 ^ (lr & 7);
            *(short4*)&Ps[n * 64 + slot * 8 + (quad & 1) * 4] = *(short4*)tmp;
        }

        // mid barrier: LDS ops only — Vs stage stays in flight (vmcnt untouched)
        asm volatile("s_waitcnt lgkmcnt(0)" ::: "memory");
        __builtin_amdgcn_s_barrier();
        __builtin_amdgcn_sched_barrier(0);

        // stage next Ks during PV (Ks reads finished before mid barrier)
        if (tt < 15) {
            int r = t >> 3, cxx = t & 7, gc = cxx ^ (r & 7);
            load_lds16(qb + (size_t)(kk + 64 + r) * D_ + gc * 8, &Ks[t * 8]);
        }

        // PV: acc[n 64][c 128] += Ps (A) x Vcur (B)
#pragma unroll
        for (int h = 0; h < 2; h++) {
            bf16x8 af[4];
#pragma unroll
            for (int i = 0; i < 4; i++) {
                int ra = wm * 64 + i * 16 + lr;
                af[i] = *(const bf16x8*)&Ps[ra * 64 + ((h * 4 + quad) ^ (lr & 7)) * 8];
            }
#pragma unroll
            for (int g = 0; g < 2; g++) {
                bf16x8 bfr[4];
#pragma unroll
                for (int j = 0; j < 4; j++) {
                    int rb = wn * 128 + (g * 4 + j) * 16 + lr;
                    bfr[j] = *(const bf16x8*)&Vcur[rb * 64 + ((h * 4 + quad) ^ (lr & 7)) * 8];
                }
#pragma unroll
                for (int mt = 0; mt < 4; mt++)
#pragma unroll
                    for (int j = 0; j < 4; j++)
                        acc[mt][g * 4 + j] = MFMA16(af[mt], bfr[j], acc[mt][g * 4 + j]);
            }
        }
        __syncthreads();   // vmcnt(0)+lgkmcnt(0): next tile's Vs/Ks landed
    }

    // rowinv: reduce partial sums across the 4 quads (Rs in dead Vs0 region)
    rsum += __shfl_xor(rsum, 16);
    rsum += __shfl_xor(rsum, 32);
    if (quad == 0) Rs[wave * 16 + lr] = 1.0f / rsum;

    // epilogue: 4 phases (h = n-half, g = c-half) through LDS Obuf[64][260]
    const float* xb = x + (size_t)b * (N_ * C_);
    float* ob = out + (size_t)b * (N_ * C_);
#pragma unroll
    for (int h = 0; h < 2; h++) {
#pragma unroll
        for (int g = 0; g < 2; g++) {
            __syncthreads();   // Obuf free; also publishes Rs on first pass
            if (wm == h && (wn >> 1) == g) {
#pragma unroll
                for (int mt = 0; mt < 4; mt++)
#pragma unroll
                    for (int nt = 0; nt < 8; nt++)
#pragma unroll
                        for (int r = 0; r < 4; r++)
                            Obuf[(mt * 16 + quad * 4 + r) * 260
                                 + (wn & 1) * 128 + nt * 16 + lr] =
                                acc[mt][nt][r];
            }
            __syncthreads();
#pragma unroll
            for (int i = 0; i < 8; i++) {
                int id = i * 512 + t;
                int rl = id >> 6;              // 0..63 (= i*8 + wave)
                int c4 = (id & 63) * 4;        // float4 col 0..252
                int n = n_blk + h * 64 + rl;
                float ri = Rs[h * 64 + rl];
                float4v o = *(const float4v*)&Obuf[rl * 260 + c4];
                size_t gidx = (size_t)n * C_ + g * 256 + c4;
                float4v xv = *(const float4v*)(xb + gidx);
                float4v res;
                res.x = xv.x + ri * o.x;
                res.y = xv.y + ri * o.y;
                res.z = xv.z + ri * o.z;
                res.w = xv.w + ri * o.w;
                *(float4v*)(ob + gidx) = res;
            }
        }
    }
}

// ---------------------------------------------------------------------------
extern "C" void kernel_launch(void* const* d_in, const int* in_sizes, int n_in,
                              void* d_out, int out_size, void* d_ws, size_t ws_size,
                              hipStream_t stream) {
    const float* x  = (const float*)d_in[0];
    const float* w1 = (const float*)d_in[1];
    const float* b1 = (const float*)d_in[2];
    const float* w2 = (const float*)d_in[3];
    const float* b2 = (const float*)d_in[4];
    float* out = (float*)d_out;

    char* ws = (char*)d_ws;
    size_t off = 0;
    __hip_bfloat16* Wbf = (__hip_bfloat16*)(ws + off); off += (size_t)OPAD * C_ * 2;
    __hip_bfloat16* xT  = (__hip_bfloat16*)(ws + off); off += (size_t)B_ * N_ * C_ * 2;
    __hip_bfloat16* qkT = (__hip_bfloat16*)(ws + off); off += (size_t)B_ * N_ * D_ * 2;
    __hip_bfloat16* v   = (__hip_bfloat16*)(ws + off); off += (size_t)B_ * C_ * N_ * 2;

    hipLaunchKernelGGL(k_cast_weights, dim3((OPAD * C_ + 255) / 256), dim3(256), 0, stream,
                       w1, w2, Wbf);
    hipLaunchKernelGGL(k_transpose_cast, dim3(N_ / 64, C_ / 64, B_), dim3(256), 0, stream,
                       x, xT);
    hipLaunchKernelGGL(k_gemm_qkv, dim3(B_, N_ / 128, OPAD / 128), dim3(256), 0, stream,
                       Wbf, xT, b1, b2, qkT, v);
    hipLaunchKernelGGL(k_fused_attn, dim3(B_, N_ / 128), dim3(512), 0, stream,
                       qkT, v, x, out);
}